// Round 16
// baseline (130.188 us; speedup 1.0000x reference)
//
#include <hip/hip_runtime.h>

// SoftDtwRkdDistance: B=32, T=96, D=128, f32 in, scalar f32 out.
// r11 best-known configuration + last-block-fused reduction:
//   K0 xn:  row squared-norms (+ resets the dp completion counter).
//   K1 csq: A+B panels in LDS with per-row slot rotation (conflict-free
//           ds_read_b128). C'=(xn_a+xn_b-2*dot)*rg2, diag-major global.
//   K2 dp:  one wave per problem; 4-deep register prefetch, 2 shfls/diag,
//           compact phase-split loops (B-side skipped where provably dead).
//           LAST block (device-scope counter) computes means + smooth-L1.
// Fallback: if ws too small for the 38 MB C buffer, run the round-3 fused kernel.

constexpr int TT = 96;
constexpr int DD = 128;
constexpr int BB = 32;
constexpr int NP = BB * BB;               // 1024
constexpr int NPAIR = BB * (BB + 1) / 2;  // 528
constexpr int NPROB = 2 * NPAIR;          // 1056
constexpr int CSZ = TT * TT;              // 9216 floats per problem
constexpr float FINF = 1e10f;
constexpr float LOG2E = 1.4426950408889634f;
constexpr float LN2 = 0.6931471805599453f;

__device__ __forceinline__ int tri_base(int a) {   // pairs with first index < a
  return a * BB - (a * (a - 1)) / 2;
}
__device__ __forceinline__ void tri_decode(int pr, int& a, int& b) {
  a = (int)((65.0f - sqrtf(4225.0f - 8.0f * (float)pr)) * 0.5f);
  while (tri_base(a + 1) <= pr) ++a;
  while (tri_base(a) > pr) --a;
  b = a + (pr - tri_base(a));
}
__device__ __forceinline__ int diag_base(int d) {
  return (d <= 95) ? ((d * (d + 1)) >> 1)
                   : 4656 + (((d - 96) * (287 - d)) >> 1);
}
// softmin in z''-domain, op order matches reference (up, left, diag)
__device__ __forceinline__ float smin2(float u, float lf, float dg) {
  float m = fmaxf(fmaxf(u, lf), dg);
  float s = __builtin_amdgcn_exp2f(u - m) + __builtin_amdgcn_exp2f(lf - m)
          + __builtin_amdgcn_exp2f(dg - m);
  return m + __builtin_amdgcn_logf(s);
}

// K0: row squared-norms xn[2][BB*TT]; also resets the dp completion counter.
__global__ void xn_kernel(const float* __restrict__ xs,
                          const float* __restrict__ xt,
                          float* __restrict__ xn,
                          int* __restrict__ counter) {
  if (blockIdx.x == 0 && threadIdx.x == 0) *counter = 0;
  int idx = blockIdx.x * 256 + threadIdx.x;
  if (idx >= 2 * BB * TT) return;
  int which = idx / (BB * TT);
  int row = idx - which * (BB * TT);
  const float* x = which ? xt : xs;
  const float4* xv = reinterpret_cast<const float4*>(x + (size_t)row * DD);
  float acc = 0.f;
#pragma unroll
  for (int k = 0; k < DD / 4; ++k) {
    float4 v = xv[k];
    acc = fmaf(v.x, v.x, acc);
    acc = fmaf(v.y, v.y, acc);
    acc = fmaf(v.z, v.z, acc);
    acc = fmaf(v.w, v.w, acc);
  }
  xn[idx] = acc;
}

// K1: C' in diag-major global layout. One 256-thread block per (pair, tensor).
// r11-proven: per-row slot-rotated LDS layout (conflict-free reads).
__global__ __launch_bounds__(256)
void csq_kernel(const float* __restrict__ xs,
                const float* __restrict__ xt,
                const float* __restrict__ xn,
                const float* __restrict__ gptr,
                float* __restrict__ Cd) {
  __shared__ __align__(16) float Cs[CSZ];   // staging aliases front (6912 floats)
  __shared__ float xna[TT];
  __shared__ float xnb[TT];

  const int pr = blockIdx.x;
  int a, b;
  tri_decode(pr, a, b);
  const int w = blockIdx.y;
  const float* x = w ? xt : xs;
  const float* xnw = xn + w * (BB * TT);
  const float* xa = x + (size_t)a * TT * DD;
  const float* xb = x + (size_t)b * TT * DD;
  const int tid = threadIdx.x;

  if (tid < TT) {
    xna[tid] = xnw[a * TT + tid];
    xnb[tid] = xnw[b * TT + tid];
  }

  // staged panels: [96 rows][9 float4 slots]; row t's logical k4 block lives
  // at slot (k4 + t/6) & 7 (slot 8 unused pad).
  float4* sa = reinterpret_cast<float4*>(Cs);          // A panel: 864 float4
  float4* sb = sa + TT * 9;                            // B panel: 864 float4

  const int wv = tid >> 6;
  const int lane = tid & 63;
  const int tx = (lane & 7) + (wv & 1) * 8;      // 0..15
  const int ty = (lane >> 3) + (wv >> 1) * 8;    // 0..15
  const int t0 = ty * 6, s0 = tx * 6;

  float acc[6][6];
#pragma unroll
  for (int r = 0; r < 6; ++r)
#pragma unroll
    for (int c = 0; c < 6; ++c) acc[r][c] = 0.f;

  const float4* ga = reinterpret_cast<const float4*>(xa);  // row stride 32
  const float4* gb = reinterpret_cast<const float4*>(xb);

  for (int d0 = 0; d0 < 4; ++d0) {     // 4 chunks of 8 float4 (32 k)
    __syncthreads();   // previous chunk's reads done before overwrite
#pragma unroll
    for (int it = 0; it < 3; ++it) {
      int idx = tid + it * 256;        // 0..767
      int t = idx >> 3, k4 = idx & 7;  // row, logical slot
      int slot = (k4 + (t / 6)) & 7;   // rotated storage slot
      sa[t * 9 + slot] = ga[t * 32 + d0 * 8 + k4];
      sb[t * 9 + slot] = gb[t * 32 + d0 * 8 + k4];
    }
    __syncthreads();
#pragma unroll
    for (int k4 = 0; k4 < 8; ++k4) {
      float4 av4[6], bv4[6];
      const int sA = (k4 + ty) & 7;    // rotated slot for this lane's A rows
      const int sB = (k4 + tx) & 7;    // rotated slot for this lane's B rows
#pragma unroll
      for (int r = 0; r < 6; ++r)
        av4[r] = sa[(t0 + r) * 9 + sA];
#pragma unroll
      for (int c = 0; c < 6; ++c)
        bv4[c] = sb[(s0 + c) * 9 + sB];
#pragma unroll
      for (int r = 0; r < 6; ++r)
#pragma unroll
        for (int c = 0; c < 6; ++c) {
          acc[r][c] = fmaf(av4[r].x, bv4[c].x, acc[r][c]);
          acc[r][c] = fmaf(av4[r].y, bv4[c].y, acc[r][c]);
          acc[r][c] = fmaf(av4[r].z, bv4[c].z, acc[r][c]);
          acc[r][c] = fmaf(av4[r].w, bv4[c].w, acc[r][c]);
        }
    }
  }
  __syncthreads();
  const float rg2 = -LOG2E / gptr[0];
#pragma unroll
  for (int r = 0; r < 6; ++r) {
    float xr = xna[t0 + r];
#pragma unroll
    for (int c = 0; c < 6; ++c) {
      float cv = xr + xnb[s0 + c] - 2.0f * acc[r][c];   // exact ref C
      Cs[(t0 + r) * TT + (s0 + c)] = cv * rg2;          // pre-scaled, row-major
    }
  }
  __syncthreads();

  // write-out: diag-major, coalesced; wave wv handles diagonals d ≡ wv (mod 4)
  const size_t qb = (size_t)(w * NPAIR + pr) * CSZ;
  for (int d = wv; d < 2 * TT - 1; d += 4) {
    int s = d <= 95 ? 0 : d - 95;
    int len = d <= 95 ? d + 1 : 191 - d;
    int base = diag_base(d);
    if (lane < len) {
      int i = s + lane;
      Cd[qb + base + lane] = Cs[i * TT + (d - i)];
    }
    if (len > 64 && lane < len - 64) {
      int i = s + 64 + lane;
      Cd[qb + base + 64 + lane] = Cs[i * TT + (d - i)];
    }
  }
}

// K2: DP. One wave per problem q = w*528 + pr. No LDS in the DP phase.
// 4-deep prefetch (slot (d-1)&3), 2 shfls/diag via shadow regs,
// compact phase-split: B-side skipped where provably NEGI.
// Last-finished block performs the final reduction (means + smooth-L1).
#define ST_R(d, qa, qb) do {                                             \
    float cA = qa, cB = qb;                                              \
    { int dn = (d) + 4;                                                  \
      if (dn <= 190) { int nb = diag_base(dn);                           \
        qa = cb[nb + l]; qb = cb[nb + 64 + l]; } }                       \
    float rA1 = __shfl(A1, lm1), rB1 = __shfl(B1, lm1);                  \
    float upA = l0 ? NEGI : rA1;                                         \
    float dgA = l0 ? NEGI : pA1;                                         \
    float upB = l0 ? rA1 : rB1;                                          \
    float dgB = l0 ? pA1 : pB1;                                          \
    float nA = cA + smin2(upA, A1, dgA);                                 \
    float nB = cB + smin2(upB, B1, dgB);                                 \
    A2 = A1; B2 = B1;                                                    \
    A1 = (l < (d) + 1) ? nA : NEGI;                                      \
    B1 = (64 + l < (d) + 1) ? nB : NEGI;                                 \
    pA1 = rA1; pB1 = rB1;                                                \
  } while (0)

#define ST_RN(d, qa, qb) do {  /* rising, B provably dead (d<=63) */     \
    float cA = qa;                                                       \
    { int dn = (d) + 4;                                                  \
      if (dn <= 190) { int nb = diag_base(dn);                           \
        qa = cb[nb + l]; qb = cb[nb + 64 + l]; } }                       \
    float rA1 = __shfl(A1, lm1);                                         \
    float upA = l0 ? NEGI : rA1;                                         \
    float dgA = l0 ? NEGI : pA1;                                         \
    float nA = cA + smin2(upA, A1, dgA);                                 \
    A2 = A1;                                                             \
    A1 = (l < (d) + 1) ? nA : NEGI;                                      \
    pA1 = rA1;                                                           \
  } while (0)

#define ST_F(d, qa, qb) do {                                             \
    float cA = qa, cB = qb;                                              \
    { int dn = (d) + 4;                                                  \
      if (dn <= 190) { int nb = diag_base(dn); qa = cb[nb + l];          \
        if (dn <= 128) qb = cb[nb + 64 + l]; } }                         \
    float rA1 = __shfl(A1, lp1), rB1 = __shfl(B1, lp1);                  \
    float lfA = l63 ? rB1 : rA1;                                         \
    float dgA = l63 ? pB1 : pA1;                                         \
    float nA = cA + smin2(A1, lfA, dgA);                                 \
    float nB = cB + smin2(B1, rB1, pB1);                                 \
    A1 = (l < 191 - (d)) ? nA : NEGI;                                    \
    B1 = (64 + l < 191 - (d)) ? nB : NEGI;                               \
    pA1 = rA1; pB1 = rB1;                                                \
  } while (0)

#define ST_FN(d, qa, qb) do {  /* falling, B provably dead (d>=129) */   \
    float cA = qa;                                                       \
    { int dn = (d) + 4;                                                  \
      if (dn <= 190) { int nb = diag_base(dn); qa = cb[nb + l]; } }      \
    float rA1 = __shfl(A1, lp1);                                         \
    float lfA = l63 ? NEGI : rA1;                                        \
    float dgA = l63 ? NEGI : pA1;                                        \
    float nA = cA + smin2(A1, lfA, dgA);                                 \
    A1 = (l < 191 - (d)) ? nA : NEGI;                                    \
    pA1 = rA1;                                                           \
  } while (0)

__global__ __launch_bounds__(64)
void dp_kernel(const float* __restrict__ Cd,
               const float* __restrict__ gptr,
               float* __restrict__ dtw,
               int* __restrict__ counter,
               float* __restrict__ out) {
  const int q = blockIdx.x;
  const int l = threadIdx.x;
  const float gamma = gptr[0];
  const float rg2 = -LOG2E / gamma;
  const float NEGI = FINF * rg2;          // invalid cell in z''-domain
  const float* __restrict__ cb = Cd + (size_t)q * CSZ;
  const int lp1 = (l + 1) & 63, lm1 = (l + 63) & 63;
  const bool l0 = (l == 0), l63 = (l == 63);

  // prefetch queue: slot (d-1)&3; preload diagonals 1..4
  float q0A, q0B, q1A, q1B, q2A, q2B, q3A, q3B;
  {
    int b1 = diag_base(1), b2 = diag_base(2), b3 = diag_base(3), b4 = diag_base(4);
    q0A = cb[b1 + l]; q0B = cb[b1 + 64 + l];
    q1A = cb[b2 + l]; q1B = cb[b2 + 64 + l];
    q2A = cb[b3 + l]; q2B = cb[b3 + 64 + l];
    q3A = cb[b4 + l]; q3B = cb[b4 + 64 + l];
  }

  // d=0 peel: r(0,0)'' = C''(0,0)
  float A1 = l0 ? cb[0] : NEGI;
  float B1 = NEGI, A2 = NEGI, B2 = NEGI;
  float pA1 = NEGI, pB1 = NEGI;   // shadow: last iter's shfl(A1/B1)

  // rising, B dead: d = 1..60 (15 groups), peel 61,62,63
  for (int g = 0; g < 15; ++g) {
    int d = 1 + g * 4;
    ST_RN(d,     q0A, q0B);
    ST_RN(d + 1, q1A, q1B);
    ST_RN(d + 2, q2A, q2B);
    ST_RN(d + 3, q3A, q3B);
  }
  ST_RN(61, q0A, q0B);
  ST_RN(62, q1A, q1B);
  ST_RN(63, q2A, q2B);

  // rising, full: d = 64, 65..92 (7 groups), peel 93,94,95
  ST_R(64, q3A, q3B);
  for (int g = 0; g < 7; ++g) {
    int d = 65 + g * 4;
    ST_R(d,     q0A, q0B);
    ST_R(d + 1, q1A, q1B);
    ST_R(d + 2, q2A, q2B);
    ST_R(d + 3, q3A, q3B);
  }
  ST_R(93, q0A, q0B);
  ST_R(94, q1A, q1B);
  ST_R(95, q2A, q2B);

  // d = 96 boundary: offsets (0, +1, 0); consumes q3, prefetches 100
  {
    float cA = q3A, cB = q3B;
    int nb = diag_base(100);
    q3A = cb[nb + l]; q3B = cb[nb + 64 + l];
    float rA1 = __shfl(A1, lp1), rB1 = __shfl(B1, lp1);
    float lfA = l63 ? rB1 : rA1;
    float lfB = rB1;
    float nA = cA + smin2(A1, lfA, A2);
    float nB = cB + smin2(B1, lfB, B2);
    A1 = (l < 95) ? nA : NEGI;          // len = 95
    B1 = (64 + l < 95) ? nB : NEGI;
    pA1 = rA1; pB1 = rB1;
  }

  // falling, full: d = 97..128 (8 groups)
  for (int g = 0; g < 8; ++g) {
    int d = 97 + g * 4;
    ST_F(d,     q0A, q0B);
    ST_F(d + 1, q1A, q1B);
    ST_F(d + 2, q2A, q2B);
    ST_F(d + 3, q3A, q3B);
  }
  // falling, B dead: d = 129..188 (15 groups), peel 189,190
  for (int g = 0; g < 15; ++g) {
    int d = 129 + g * 4;
    ST_FN(d,     q0A, q0B);
    ST_FN(d + 1, q1A, q1B);
    ST_FN(d + 2, q2A, q2B);
    ST_FN(d + 3, q3A, q3B);
  }
  ST_FN(189, q0A, q0B);
  ST_FN(190, q1A, q1B);

  // cell (95,95) = position 0 of diag 190 -> lane 0, A1
  if (l0) {
    int w = q >= NPAIR ? 1 : 0;
    int pr = q - w * NPAIR;
    int a, b;
    tri_decode(pr, a, b);
    float v = A1 * (-gamma * LN2);       // back to r-domain
    dtw[w * NP + a * BB + b] = v;
    dtw[w * NP + b * BB + a] = v;
  }

  // ---- last-block-done reduction (means + smooth-L1) ----
  __threadfence();                       // make dtw writes device-visible
  __shared__ int is_last;
  if (l == 0) {
    int prev = atomicAdd(counter, 1);    // device-scope by default
    is_last = (prev == NPROB - 1);
  }
  __syncthreads();
  if (!is_last) return;
  __threadfence();                       // acquire: see all blocks' dtw

  __shared__ double sh[64];
  double ss = 0, st = 0;
  for (int k = l; k < NP; k += 64) {
    ss += (double)dtw[k];
    st += (double)dtw[NP + k];
  }
  sh[l] = ss; __syncthreads();
  for (int o = 32; o > 0; o >>= 1) { if (l < o) sh[l] += sh[l + o]; __syncthreads(); }
  double sum_s = sh[0]; __syncthreads();
  sh[l] = st; __syncthreads();
  for (int o = 32; o > 0; o >>= 1) { if (l < o) sh[l] += sh[l + o]; __syncthreads(); }
  double sum_t = sh[0]; __syncthreads();

  float mean_s = (float)(sum_s / NP);
  float mean_t = (float)(sum_t / NP);

  double acc = 0;
  for (int k = l; k < NP; k += 64) {
    float pred = dtw[k] / mean_s;
    float targ = dtw[NP + k] / mean_t;
    float d = pred - targ;
    float ad = fabsf(d);
    float v = ad < 1.f ? 0.5f * d * d : ad - 0.5f;
    acc += (double)v;
  }
  sh[l] = acc; __syncthreads();
  for (int o = 32; o > 0; o >>= 1) { if (l < o) sh[l] += sh[l + o]; __syncthreads(); }
  if (l == 0) out[0] = (float)(sh[0] / NP);
}

// ---------------- Fallback fused kernel (round-3, proven) ----------------
__global__ __launch_bounds__(256)
void sdtw_fused_kernel(const float* __restrict__ xs,
                       const float* __restrict__ xt,
                       const float* __restrict__ xn,
                       const float* __restrict__ gptr,
                       float* __restrict__ dtw) {
  __shared__ __align__(16) float Cs[TT * TT];
  __shared__ float xna[TT];
  __shared__ float xnb[TT];

  const int pr = blockIdx.x;
  int a, b;
  tri_decode(pr, a, b);
  const int w = blockIdx.y;
  const float* x = w ? xt : xs;
  const float* xnw = xn + w * (BB * TT);
  const float* xa = x + (size_t)a * TT * DD;
  const float* xb = x + (size_t)b * TT * DD;
  const int tid = threadIdx.x;

  if (tid < TT) {
    xna[tid] = xnw[a * TT + tid];
    xnb[tid] = xnw[b * TT + tid];
  }
  constexpr int SROW = 36;
  float* xa_s = Cs;
  float* xb_s = Cs + TT * SROW;
  const int wv = tid >> 6;
  const int lane = tid & 63;
  const int tx = (lane & 7) + (wv & 1) * 8;
  const int ty = (lane >> 3) + (wv >> 1) * 8;
  const int t0 = ty * 6, s0 = tx * 6;
  float acc[6][6];
#pragma unroll
  for (int r = 0; r < 6; ++r)
#pragma unroll
    for (int c = 0; c < 6; ++c) acc[r][c] = 0.f;
  for (int d0 = 0; d0 < DD; d0 += 32) {
    __syncthreads();
    const float4* ga = reinterpret_cast<const float4*>(xa + d0);
    const float4* gb = reinterpret_cast<const float4*>(xb + d0);
    float4* sa = reinterpret_cast<float4*>(xa_s);
    float4* sb = reinterpret_cast<float4*>(xb_s);
#pragma unroll
    for (int it = 0; it < 3; ++it) {
      int idx = tid + it * 256;
      int t = idx >> 3, k4 = idx & 7;
      sa[t * (SROW / 4) + k4] = ga[t * (DD / 4) + k4];
      sb[t * (SROW / 4) + k4] = gb[t * (DD / 4) + k4];
    }
    __syncthreads();
#pragma unroll
    for (int k4 = 0; k4 < 8; ++k4) {
      float4 av4[6], bv4[6];
#pragma unroll
      for (int r = 0; r < 6; ++r)
        av4[r] = reinterpret_cast<const float4*>(xa_s + (t0 + r) * SROW)[k4];
#pragma unroll
      for (int c = 0; c < 6; ++c)
        bv4[c] = reinterpret_cast<const float4*>(xb_s + (s0 + c) * SROW)[k4];
#pragma unroll
      for (int r = 0; r < 6; ++r)
#pragma unroll
        for (int c = 0; c < 6; ++c) {
          acc[r][c] = fmaf(av4[r].x, bv4[c].x, acc[r][c]);
          acc[r][c] = fmaf(av4[r].y, bv4[c].y, acc[r][c]);
          acc[r][c] = fmaf(av4[r].z, bv4[c].z, acc[r][c]);
          acc[r][c] = fmaf(av4[r].w, bv4[c].w, acc[r][c]);
        }
    }
  }
  __syncthreads();
#pragma unroll
  for (int r = 0; r < 6; ++r) {
    float xr = xna[t0 + r];
#pragma unroll
    for (int c = 0; c < 6; ++c)
      Cs[(t0 + r) * TT + (s0 + c)] = xr + xnb[s0 + c] - 2.0f * acc[r][c];
  }
  __syncthreads();
  if (tid >= 64) return;

  const float gamma = gptr[0];
  const float rg = -1.0f / gamma;
  const int lm1 = (lane + 63) & 63;
  float A1 = FINF, B1 = FINF, A2 = FINF, B2 = FINF;
  for (int d = 0; d < 2 * TT - 1; ++d) {
    int jA = d - lane;
    bool vA = (jA >= 0) && (jA < TT);
    float cA = Cs[vA ? lane * TT + jA : 0];
    int iB = 64 + lane;
    int jB = d - iB;
    bool vB = (lane < 32) && (jB >= 0) && (jB < TT);
    float cB = Cs[vB ? iB * TT + jB : 0];
    float rA1 = __shfl(A1, lm1);
    float rB1 = __shfl(B1, lm1);
    float rA2 = __shfl(A2, lm1);
    float rB2 = __shfl(B2, lm1);
    const bool l0 = (lane == 0);
    float upA = l0 ? FINF : rA1;
    float dgA = l0 ? FINF : rA2;
    float upB = l0 ? rA1 : rB1;
    float dgB = l0 ? rA2 : rB2;
    float z0 = upA * rg, z1 = A1 * rg, z2 = dgA * rg;
    float m = fmaxf(fmaxf(z0, z1), z2);
    float s = expf(z0 - m) + expf(z1 - m) + expf(z2 - m);
    float sminA = -gamma * (m + logf(s));
    if (d == 0) sminA = 0.f;
    float y0 = upB * rg, y1 = B1 * rg, y2 = dgB * rg;
    float mb = fmaxf(fmaxf(y0, y1), y2);
    float sb2 = expf(y0 - mb) + expf(y1 - mb) + expf(y2 - mb);
    float sminB = -gamma * (mb + logf(sb2));
    float nA = vA ? cA + sminA : FINF;
    float nB = vB ? cB + sminB : FINF;
    A2 = A1; B2 = B1; A1 = nA; B1 = nB;
  }
  if (lane == 31) {
    float v = B1;
    dtw[w * NP + a * BB + b] = v;
    dtw[w * NP + b * BB + a] = v;
  }
}

// K3 (fallback path): means + normalized smooth-L1 (single block).
__global__ void reduce_kernel(const float* __restrict__ dtw,
                              float* __restrict__ out) {
  __shared__ double sh[256];
  const int tid = threadIdx.x;
  double ss = 0, st = 0;
  for (int k = tid; k < NP; k += 256) {
    ss += (double)dtw[k];
    st += (double)dtw[NP + k];
  }
  sh[tid] = ss; __syncthreads();
  for (int o = 128; o > 0; o >>= 1) { if (tid < o) sh[tid] += sh[tid + o]; __syncthreads(); }
  double sum_s = sh[0]; __syncthreads();
  sh[tid] = st; __syncthreads();
  for (int o = 128; o > 0; o >>= 1) { if (tid < o) sh[tid] += sh[tid + o]; __syncthreads(); }
  double sum_t = sh[0]; __syncthreads();

  float mean_s = (float)(sum_s / NP);
  float mean_t = (float)(sum_t / NP);

  double acc = 0;
  for (int k = tid; k < NP; k += 256) {
    float pred = dtw[k] / mean_s;
    float targ = dtw[NP + k] / mean_t;
    float d = pred - targ;
    float ad = fabsf(d);
    float v = ad < 1.f ? 0.5f * d * d : ad - 0.5f;
    acc += (double)v;
  }
  sh[tid] = acc; __syncthreads();
  for (int o = 128; o > 0; o >>= 1) { if (tid < o) sh[tid] += sh[tid + o]; __syncthreads(); }
  if (tid == 0) out[0] = (float)(sh[0] / NP);
}

extern "C" void kernel_launch(void* const* d_in, const int* in_sizes, int n_in,
                              void* d_out, int out_size, void* d_ws, size_t ws_size,
                              hipStream_t stream) {
  const float* student = (const float*)d_in[0];
  const float* teacher = (const float*)d_in[1];
  const float* gamma   = (const float*)d_in[2];
  float* ws = (float*)d_ws;

  const size_t cd_floats = (size_t)NPROB * CSZ;              // 9,732,096
  const size_t need = (cd_floats + 2 * NP + 2 * BB * TT + 1) * sizeof(float);

  if (ws_size >= need) {
    float* Cd  = ws;
    float* dtw = ws + cd_floats;
    float* xnb = dtw + 2 * NP;
    int* counter = (int*)(xnb + 2 * BB * TT);
    xn_kernel<<<24, 256, 0, stream>>>(student, teacher, xnb, counter);
    csq_kernel<<<dim3(NPAIR, 2), 256, 0, stream>>>(student, teacher, xnb, gamma, Cd);
    dp_kernel<<<NPROB, 64, 0, stream>>>(Cd, gamma, dtw, counter, (float*)d_out);
  } else {
    float* dtw = ws;
    float* xnb = ws + 2 * NP;
    int* counter = (int*)(xnb + 2 * BB * TT);
    xn_kernel<<<24, 256, 0, stream>>>(student, teacher, xnb, counter);
    sdtw_fused_kernel<<<dim3(NPAIR, 2), 256, 0, stream>>>(student, teacher, xnb, gamma, dtw);
    reduce_kernel<<<1, 256, 0, stream>>>(dtw, (float*)d_out);
  }
}

// Round 17
// 93.565 us; speedup vs baseline: 1.3914x; 1.3914x over previous
//
#include <hip/hip_runtime.h>

// SoftDtwRkdDistance: B=32, T=96, D=128, f32 in, scalar f32 out.
// r11 BEST-KNOWN configuration (92.9 us), restored verbatim:
//   K0 xn:  row squared-norms.
//   K1 csq: A+B panels in LDS with per-row slot rotation (conflict-free
//           ds_read_b128). C'=(xn_a+xn_b-2*dot)*rg2, diag-major global.
//   K2 dp:  one wave per problem; 4-deep register prefetch, 2 shfls/diag,
//           compact phase-split loops (B-side skipped where provably dead).
//   K3 reduce: means + smooth-L1.
// Fallback: if ws too small for the 38 MB C buffer, run the round-3 fused kernel.

constexpr int TT = 96;
constexpr int DD = 128;
constexpr int BB = 32;
constexpr int NP = BB * BB;               // 1024
constexpr int NPAIR = BB * (BB + 1) / 2;  // 528
constexpr int NPROB = 2 * NPAIR;          // 1056
constexpr int CSZ = TT * TT;              // 9216 floats per problem
constexpr float FINF = 1e10f;
constexpr float LOG2E = 1.4426950408889634f;
constexpr float LN2 = 0.6931471805599453f;

__device__ __forceinline__ int tri_base(int a) {   // pairs with first index < a
  return a * BB - (a * (a - 1)) / 2;
}
__device__ __forceinline__ void tri_decode(int pr, int& a, int& b) {
  a = (int)((65.0f - sqrtf(4225.0f - 8.0f * (float)pr)) * 0.5f);
  while (tri_base(a + 1) <= pr) ++a;
  while (tri_base(a) > pr) --a;
  b = a + (pr - tri_base(a));
}
__device__ __forceinline__ int diag_base(int d) {
  return (d <= 95) ? ((d * (d + 1)) >> 1)
                   : 4656 + (((d - 96) * (287 - d)) >> 1);
}
// softmin in z''-domain, op order matches reference (up, left, diag)
__device__ __forceinline__ float smin2(float u, float lf, float dg) {
  float m = fmaxf(fmaxf(u, lf), dg);
  float s = __builtin_amdgcn_exp2f(u - m) + __builtin_amdgcn_exp2f(lf - m)
          + __builtin_amdgcn_exp2f(dg - m);
  return m + __builtin_amdgcn_logf(s);
}

// K0: row squared-norms xn[2][BB*TT]
__global__ void xn_kernel(const float* __restrict__ xs,
                          const float* __restrict__ xt,
                          float* __restrict__ xn) {
  int idx = blockIdx.x * 256 + threadIdx.x;
  if (idx >= 2 * BB * TT) return;
  int which = idx / (BB * TT);
  int row = idx - which * (BB * TT);
  const float* x = which ? xt : xs;
  const float4* xv = reinterpret_cast<const float4*>(x + (size_t)row * DD);
  float acc = 0.f;
#pragma unroll
  for (int k = 0; k < DD / 4; ++k) {
    float4 v = xv[k];
    acc = fmaf(v.x, v.x, acc);
    acc = fmaf(v.y, v.y, acc);
    acc = fmaf(v.z, v.z, acc);
    acc = fmaf(v.w, v.w, acc);
  }
  xn[idx] = acc;
}

// K1: C' in diag-major global layout. One 256-thread block per (pair, tensor).
// r11-proven: per-row slot-rotated LDS layout (conflict-free reads).
__global__ __launch_bounds__(256)
void csq_kernel(const float* __restrict__ xs,
                const float* __restrict__ xt,
                const float* __restrict__ xn,
                const float* __restrict__ gptr,
                float* __restrict__ Cd) {
  __shared__ __align__(16) float Cs[CSZ];   // staging aliases front (6912 floats)
  __shared__ float xna[TT];
  __shared__ float xnb[TT];

  const int pr = blockIdx.x;
  int a, b;
  tri_decode(pr, a, b);
  const int w = blockIdx.y;
  const float* x = w ? xt : xs;
  const float* xnw = xn + w * (BB * TT);
  const float* xa = x + (size_t)a * TT * DD;
  const float* xb = x + (size_t)b * TT * DD;
  const int tid = threadIdx.x;

  if (tid < TT) {
    xna[tid] = xnw[a * TT + tid];
    xnb[tid] = xnw[b * TT + tid];
  }

  // staged panels: [96 rows][9 float4 slots]; row t's logical k4 block lives
  // at slot (k4 + t/6) & 7 (slot 8 unused pad).
  float4* sa = reinterpret_cast<float4*>(Cs);          // A panel: 864 float4
  float4* sb = sa + TT * 9;                            // B panel: 864 float4

  const int wv = tid >> 6;
  const int lane = tid & 63;
  const int tx = (lane & 7) + (wv & 1) * 8;      // 0..15
  const int ty = (lane >> 3) + (wv >> 1) * 8;    // 0..15
  const int t0 = ty * 6, s0 = tx * 6;

  float acc[6][6];
#pragma unroll
  for (int r = 0; r < 6; ++r)
#pragma unroll
    for (int c = 0; c < 6; ++c) acc[r][c] = 0.f;

  const float4* ga = reinterpret_cast<const float4*>(xa);  // row stride 32
  const float4* gb = reinterpret_cast<const float4*>(xb);

  for (int d0 = 0; d0 < 4; ++d0) {     // 4 chunks of 8 float4 (32 k)
    __syncthreads();   // previous chunk's reads done before overwrite
#pragma unroll
    for (int it = 0; it < 3; ++it) {
      int idx = tid + it * 256;        // 0..767
      int t = idx >> 3, k4 = idx & 7;  // row, logical slot
      int slot = (k4 + (t / 6)) & 7;   // rotated storage slot
      sa[t * 9 + slot] = ga[t * 32 + d0 * 8 + k4];
      sb[t * 9 + slot] = gb[t * 32 + d0 * 8 + k4];
    }
    __syncthreads();
#pragma unroll
    for (int k4 = 0; k4 < 8; ++k4) {
      float4 av4[6], bv4[6];
      const int sA = (k4 + ty) & 7;    // rotated slot for this lane's A rows
      const int sB = (k4 + tx) & 7;    // rotated slot for this lane's B rows
#pragma unroll
      for (int r = 0; r < 6; ++r)
        av4[r] = sa[(t0 + r) * 9 + sA];
#pragma unroll
      for (int c = 0; c < 6; ++c)
        bv4[c] = sb[(s0 + c) * 9 + sB];
#pragma unroll
      for (int r = 0; r < 6; ++r)
#pragma unroll
        for (int c = 0; c < 6; ++c) {
          acc[r][c] = fmaf(av4[r].x, bv4[c].x, acc[r][c]);
          acc[r][c] = fmaf(av4[r].y, bv4[c].y, acc[r][c]);
          acc[r][c] = fmaf(av4[r].z, bv4[c].z, acc[r][c]);
          acc[r][c] = fmaf(av4[r].w, bv4[c].w, acc[r][c]);
        }
    }
  }
  __syncthreads();
  const float rg2 = -LOG2E / gptr[0];
#pragma unroll
  for (int r = 0; r < 6; ++r) {
    float xr = xna[t0 + r];
#pragma unroll
    for (int c = 0; c < 6; ++c) {
      float cv = xr + xnb[s0 + c] - 2.0f * acc[r][c];   // exact ref C
      Cs[(t0 + r) * TT + (s0 + c)] = cv * rg2;          // pre-scaled, row-major
    }
  }
  __syncthreads();

  // write-out: diag-major, coalesced; wave wv handles diagonals d ≡ wv (mod 4)
  const size_t qb = (size_t)(w * NPAIR + pr) * CSZ;
  for (int d = wv; d < 2 * TT - 1; d += 4) {
    int s = d <= 95 ? 0 : d - 95;
    int len = d <= 95 ? d + 1 : 191 - d;
    int base = diag_base(d);
    if (lane < len) {
      int i = s + lane;
      Cd[qb + base + lane] = Cs[i * TT + (d - i)];
    }
    if (len > 64 && lane < len - 64) {
      int i = s + 64 + lane;
      Cd[qb + base + 64 + lane] = Cs[i * TT + (d - i)];
    }
  }
}

// K2: DP. One wave per problem q = w*528 + pr. No LDS.
// 4-deep prefetch (slot (d-1)&3), 2 shfls/diag via shadow regs,
// compact phase-split: B-side skipped where provably NEGI.
#define ST_R(d, qa, qb) do {                                             \
    float cA = qa, cB = qb;                                              \
    { int dn = (d) + 4;                                                  \
      if (dn <= 190) { int nb = diag_base(dn);                           \
        qa = cb[nb + l]; qb = cb[nb + 64 + l]; } }                       \
    float rA1 = __shfl(A1, lm1), rB1 = __shfl(B1, lm1);                  \
    float upA = l0 ? NEGI : rA1;                                         \
    float dgA = l0 ? NEGI : pA1;                                         \
    float upB = l0 ? rA1 : rB1;                                          \
    float dgB = l0 ? pA1 : pB1;                                          \
    float nA = cA + smin2(upA, A1, dgA);                                 \
    float nB = cB + smin2(upB, B1, dgB);                                 \
    A2 = A1; B2 = B1;                                                    \
    A1 = (l < (d) + 1) ? nA : NEGI;                                      \
    B1 = (64 + l < (d) + 1) ? nB : NEGI;                                 \
    pA1 = rA1; pB1 = rB1;                                                \
  } while (0)

#define ST_RN(d, qa, qb) do {  /* rising, B provably dead (d<=63) */     \
    float cA = qa;                                                       \
    { int dn = (d) + 4;                                                  \
      if (dn <= 190) { int nb = diag_base(dn);                           \
        qa = cb[nb + l]; qb = cb[nb + 64 + l]; } }                       \
    float rA1 = __shfl(A1, lm1);                                         \
    float upA = l0 ? NEGI : rA1;                                         \
    float dgA = l0 ? NEGI : pA1;                                         \
    float nA = cA + smin2(upA, A1, dgA);                                 \
    A2 = A1;                                                             \
    A1 = (l < (d) + 1) ? nA : NEGI;                                      \
    pA1 = rA1;                                                           \
  } while (0)

#define ST_F(d, qa, qb) do {                                             \
    float cA = qa, cB = qb;                                              \
    { int dn = (d) + 4;                                                  \
      if (dn <= 190) { int nb = diag_base(dn); qa = cb[nb + l];          \
        if (dn <= 128) qb = cb[nb + 64 + l]; } }                         \
    float rA1 = __shfl(A1, lp1), rB1 = __shfl(B1, lp1);                  \
    float lfA = l63 ? rB1 : rA1;                                         \
    float dgA = l63 ? pB1 : pA1;                                         \
    float nA = cA + smin2(A1, lfA, dgA);                                 \
    float nB = cB + smin2(B1, rB1, pB1);                                 \
    A1 = (l < 191 - (d)) ? nA : NEGI;                                    \
    B1 = (64 + l < 191 - (d)) ? nB : NEGI;                               \
    pA1 = rA1; pB1 = rB1;                                                \
  } while (0)

#define ST_FN(d, qa, qb) do {  /* falling, B provably dead (d>=129) */   \
    float cA = qa;                                                       \
    { int dn = (d) + 4;                                                  \
      if (dn <= 190) { int nb = diag_base(dn); qa = cb[nb + l]; } }      \
    float rA1 = __shfl(A1, lp1);                                         \
    float lfA = l63 ? NEGI : rA1;                                        \
    float dgA = l63 ? NEGI : pA1;                                        \
    float nA = cA + smin2(A1, lfA, dgA);                                 \
    A1 = (l < 191 - (d)) ? nA : NEGI;                                    \
    pA1 = rA1;                                                           \
  } while (0)

__global__ __launch_bounds__(64)
void dp_kernel(const float* __restrict__ Cd,
               const float* __restrict__ gptr,
               float* __restrict__ dtw) {
  const int q = blockIdx.x;
  const int l = threadIdx.x;
  const float gamma = gptr[0];
  const float rg2 = -LOG2E / gamma;
  const float NEGI = FINF * rg2;          // invalid cell in z''-domain
  const float* __restrict__ cb = Cd + (size_t)q * CSZ;
  const int lp1 = (l + 1) & 63, lm1 = (l + 63) & 63;
  const bool l0 = (l == 0), l63 = (l == 63);

  // prefetch queue: slot (d-1)&3; preload diagonals 1..4
  float q0A, q0B, q1A, q1B, q2A, q2B, q3A, q3B;
  {
    int b1 = diag_base(1), b2 = diag_base(2), b3 = diag_base(3), b4 = diag_base(4);
    q0A = cb[b1 + l]; q0B = cb[b1 + 64 + l];
    q1A = cb[b2 + l]; q1B = cb[b2 + 64 + l];
    q2A = cb[b3 + l]; q2B = cb[b3 + 64 + l];
    q3A = cb[b4 + l]; q3B = cb[b4 + 64 + l];
  }

  // d=0 peel: r(0,0)'' = C''(0,0)
  float A1 = l0 ? cb[0] : NEGI;
  float B1 = NEGI, A2 = NEGI, B2 = NEGI;
  float pA1 = NEGI, pB1 = NEGI;   // shadow: last iter's shfl(A1/B1)

  // rising, B dead: d = 1..60 (15 groups), peel 61,62,63
  for (int g = 0; g < 15; ++g) {
    int d = 1 + g * 4;
    ST_RN(d,     q0A, q0B);
    ST_RN(d + 1, q1A, q1B);
    ST_RN(d + 2, q2A, q2B);
    ST_RN(d + 3, q3A, q3B);
  }
  ST_RN(61, q0A, q0B);
  ST_RN(62, q1A, q1B);
  ST_RN(63, q2A, q2B);

  // rising, full: d = 64, 65..92 (7 groups), peel 93,94,95
  ST_R(64, q3A, q3B);
  for (int g = 0; g < 7; ++g) {
    int d = 65 + g * 4;
    ST_R(d,     q0A, q0B);
    ST_R(d + 1, q1A, q1B);
    ST_R(d + 2, q2A, q2B);
    ST_R(d + 3, q3A, q3B);
  }
  ST_R(93, q0A, q0B);
  ST_R(94, q1A, q1B);
  ST_R(95, q2A, q2B);

  // d = 96 boundary: offsets (0, +1, 0); consumes q3, prefetches 100
  {
    float cA = q3A, cB = q3B;
    int nb = diag_base(100);
    q3A = cb[nb + l]; q3B = cb[nb + 64 + l];
    float rA1 = __shfl(A1, lp1), rB1 = __shfl(B1, lp1);
    float lfA = l63 ? rB1 : rA1;
    float lfB = rB1;
    float nA = cA + smin2(A1, lfA, A2);
    float nB = cB + smin2(B1, lfB, B2);
    A1 = (l < 95) ? nA : NEGI;          // len = 95
    B1 = (64 + l < 95) ? nB : NEGI;
    pA1 = rA1; pB1 = rB1;
  }

  // falling, full: d = 97..128 (8 groups)
  for (int g = 0; g < 8; ++g) {
    int d = 97 + g * 4;
    ST_F(d,     q0A, q0B);
    ST_F(d + 1, q1A, q1B);
    ST_F(d + 2, q2A, q2B);
    ST_F(d + 3, q3A, q3B);
  }
  // falling, B dead: d = 129..188 (15 groups), peel 189,190
  for (int g = 0; g < 15; ++g) {
    int d = 129 + g * 4;
    ST_FN(d,     q0A, q0B);
    ST_FN(d + 1, q1A, q1B);
    ST_FN(d + 2, q2A, q2B);
    ST_FN(d + 3, q3A, q3B);
  }
  ST_FN(189, q0A, q0B);
  ST_FN(190, q1A, q1B);

  // cell (95,95) = position 0 of diag 190 -> lane 0, A1
  if (l0) {
    int w = q >= NPAIR ? 1 : 0;
    int pr = q - w * NPAIR;
    int a, b;
    tri_decode(pr, a, b);
    float v = A1 * (-gamma * LN2);       // back to r-domain
    dtw[w * NP + a * BB + b] = v;
    dtw[w * NP + b * BB + a] = v;
  }
}

// ---------------- Fallback fused kernel (round-3, proven) ----------------
__global__ __launch_bounds__(256)
void sdtw_fused_kernel(const float* __restrict__ xs,
                       const float* __restrict__ xt,
                       const float* __restrict__ xn,
                       const float* __restrict__ gptr,
                       float* __restrict__ dtw) {
  __shared__ __align__(16) float Cs[TT * TT];
  __shared__ float xna[TT];
  __shared__ float xnb[TT];

  const int pr = blockIdx.x;
  int a, b;
  tri_decode(pr, a, b);
  const int w = blockIdx.y;
  const float* x = w ? xt : xs;
  const float* xnw = xn + w * (BB * TT);
  const float* xa = x + (size_t)a * TT * DD;
  const float* xb = x + (size_t)b * TT * DD;
  const int tid = threadIdx.x;

  if (tid < TT) {
    xna[tid] = xnw[a * TT + tid];
    xnb[tid] = xnw[b * TT + tid];
  }
  constexpr int SROW = 36;
  float* xa_s = Cs;
  float* xb_s = Cs + TT * SROW;
  const int wv = tid >> 6;
  const int lane = tid & 63;
  const int tx = (lane & 7) + (wv & 1) * 8;
  const int ty = (lane >> 3) + (wv >> 1) * 8;
  const int t0 = ty * 6, s0 = tx * 6;
  float acc[6][6];
#pragma unroll
  for (int r = 0; r < 6; ++r)
#pragma unroll
    for (int c = 0; c < 6; ++c) acc[r][c] = 0.f;
  for (int d0 = 0; d0 < DD; d0 += 32) {
    __syncthreads();
    const float4* ga = reinterpret_cast<const float4*>(xa + d0);
    const float4* gb = reinterpret_cast<const float4*>(xb + d0);
    float4* sa = reinterpret_cast<float4*>(xa_s);
    float4* sb = reinterpret_cast<float4*>(xb_s);
#pragma unroll
    for (int it = 0; it < 3; ++it) {
      int idx = tid + it * 256;
      int t = idx >> 3, k4 = idx & 7;
      sa[t * (SROW / 4) + k4] = ga[t * (DD / 4) + k4];
      sb[t * (SROW / 4) + k4] = gb[t * (DD / 4) + k4];
    }
    __syncthreads();
#pragma unroll
    for (int k4 = 0; k4 < 8; ++k4) {
      float4 av4[6], bv4[6];
#pragma unroll
      for (int r = 0; r < 6; ++r)
        av4[r] = reinterpret_cast<const float4*>(xa_s + (t0 + r) * SROW)[k4];
#pragma unroll
      for (int c = 0; c < 6; ++c)
        bv4[c] = reinterpret_cast<const float4*>(xb_s + (s0 + c) * SROW)[k4];
#pragma unroll
      for (int r = 0; r < 6; ++r)
#pragma unroll
        for (int c = 0; c < 6; ++c) {
          acc[r][c] = fmaf(av4[r].x, bv4[c].x, acc[r][c]);
          acc[r][c] = fmaf(av4[r].y, bv4[c].y, acc[r][c]);
          acc[r][c] = fmaf(av4[r].z, bv4[c].z, acc[r][c]);
          acc[r][c] = fmaf(av4[r].w, bv4[c].w, acc[r][c]);
        }
    }
  }
  __syncthreads();
#pragma unroll
  for (int r = 0; r < 6; ++r) {
    float xr = xna[t0 + r];
#pragma unroll
    for (int c = 0; c < 6; ++c)
      Cs[(t0 + r) * TT + (s0 + c)] = xr + xnb[s0 + c] - 2.0f * acc[r][c];
  }
  __syncthreads();
  if (tid >= 64) return;

  const float gamma = gptr[0];
  const float rg = -1.0f / gamma;
  const int lm1 = (lane + 63) & 63;
  float A1 = FINF, B1 = FINF, A2 = FINF, B2 = FINF;
  for (int d = 0; d < 2 * TT - 1; ++d) {
    int jA = d - lane;
    bool vA = (jA >= 0) && (jA < TT);
    float cA = Cs[vA ? lane * TT + jA : 0];
    int iB = 64 + lane;
    int jB = d - iB;
    bool vB = (lane < 32) && (jB >= 0) && (jB < TT);
    float cB = Cs[vB ? iB * TT + jB : 0];
    float rA1 = __shfl(A1, lm1);
    float rB1 = __shfl(B1, lm1);
    float rA2 = __shfl(A2, lm1);
    float rB2 = __shfl(B2, lm1);
    const bool l0 = (lane == 0);
    float upA = l0 ? FINF : rA1;
    float dgA = l0 ? FINF : rA2;
    float upB = l0 ? rA1 : rB1;
    float dgB = l0 ? rA2 : rB2;
    float z0 = upA * rg, z1 = A1 * rg, z2 = dgA * rg;
    float m = fmaxf(fmaxf(z0, z1), z2);
    float s = expf(z0 - m) + expf(z1 - m) + expf(z2 - m);
    float sminA = -gamma * (m + logf(s));
    if (d == 0) sminA = 0.f;
    float y0 = upB * rg, y1 = B1 * rg, y2 = dgB * rg;
    float mb = fmaxf(fmaxf(y0, y1), y2);
    float sb2 = expf(y0 - mb) + expf(y1 - mb) + expf(y2 - mb);
    float sminB = -gamma * (mb + logf(sb2));
    float nA = vA ? cA + sminA : FINF;
    float nB = vB ? cB + sminB : FINF;
    A2 = A1; B2 = B1; A1 = nA; B1 = nB;
  }
  if (lane == 31) {
    float v = B1;
    dtw[w * NP + a * BB + b] = v;
    dtw[w * NP + b * BB + a] = v;
  }
}

// K3: means + normalized smooth-L1 (single block).
__global__ void reduce_kernel(const float* __restrict__ dtw,
                              float* __restrict__ out) {
  __shared__ double sh[256];
  const int tid = threadIdx.x;
  double ss = 0, st = 0;
  for (int k = tid; k < NP; k += 256) {
    ss += (double)dtw[k];
    st += (double)dtw[NP + k];
  }
  sh[tid] = ss; __syncthreads();
  for (int o = 128; o > 0; o >>= 1) { if (tid < o) sh[tid] += sh[tid + o]; __syncthreads(); }
  double sum_s = sh[0]; __syncthreads();
  sh[tid] = st; __syncthreads();
  for (int o = 128; o > 0; o >>= 1) { if (tid < o) sh[tid] += sh[tid + o]; __syncthreads(); }
  double sum_t = sh[0]; __syncthreads();

  float mean_s = (float)(sum_s / NP);
  float mean_t = (float)(sum_t / NP);

  double acc = 0;
  for (int k = tid; k < NP; k += 256) {
    float pred = dtw[k] / mean_s;
    float targ = dtw[NP + k] / mean_t;
    float d = pred - targ;
    float ad = fabsf(d);
    float v = ad < 1.f ? 0.5f * d * d : ad - 0.5f;
    acc += (double)v;
  }
  sh[tid] = acc; __syncthreads();
  for (int o = 128; o > 0; o >>= 1) { if (tid < o) sh[tid] += sh[tid + o]; __syncthreads(); }
  if (tid == 0) out[0] = (float)(sh[0] / NP);
}

extern "C" void kernel_launch(void* const* d_in, const int* in_sizes, int n_in,
                              void* d_out, int out_size, void* d_ws, size_t ws_size,
                              hipStream_t stream) {
  const float* student = (const float*)d_in[0];
  const float* teacher = (const float*)d_in[1];
  const float* gamma   = (const float*)d_in[2];
  float* ws = (float*)d_ws;

  const size_t cd_floats = (size_t)NPROB * CSZ;              // 9,732,096
  const size_t need = (cd_floats + 2 * NP + 2 * BB * TT) * sizeof(float);

  if (ws_size >= need) {
    float* Cd  = ws;
    float* dtw = ws + cd_floats;
    float* xnb = dtw + 2 * NP;
    xn_kernel<<<24, 256, 0, stream>>>(student, teacher, xnb);
    csq_kernel<<<dim3(NPAIR, 2), 256, 0, stream>>>(student, teacher, xnb, gamma, Cd);
    dp_kernel<<<NPROB, 64, 0, stream>>>(Cd, gamma, dtw);
    reduce_kernel<<<1, 256, 0, stream>>>(dtw, (float*)d_out);
  } else {
    float* dtw = ws;
    float* xnb = ws + 2 * NP;
    xn_kernel<<<24, 256, 0, stream>>>(student, teacher, xnb);
    sdtw_fused_kernel<<<dim3(NPAIR, 2), 256, 0, stream>>>(student, teacher, xnb, gamma, dtw);
    reduce_kernel<<<1, 256, 0, stream>>>(dtw, (float*)d_out);
  }
}